// Round 14
// baseline (384.680 us; speedup 1.0000x reference)
//
#include <hip/hip_runtime.h>
#include <hip/hip_bf16.h>

typedef __attribute__((ext_vector_type(8))) short short8;
typedef __attribute__((ext_vector_type(4))) float f32x4;
typedef __attribute__((ext_vector_type(16))) float f32x16;
typedef unsigned short ushort_t;
typedef unsigned int uint_t;

#define LOG2E 1.4426950408889634f

#if __has_builtin(__builtin_amdgcn_exp2f)
#define EXP2(x) __builtin_amdgcn_exp2f(x)
#else
#define EXP2(x) exp2f(x)
#endif

__device__ __forceinline__ ushort_t f2bf(float f) {
    union { float f; unsigned int i; } x; x.f = f;
    unsigned int r = x.i + 0x7FFF + ((x.i >> 16) & 1);   // RNE
    return (ushort_t)(r >> 16);
}
__device__ __forceinline__ float bf2f(ushort_t u) {
    union { unsigned int i; float f; } x; x.i = ((unsigned int)u) << 16; return x.f;
}
__device__ __forceinline__ uint_t cvtpk(float lo, float hi) {
    uint_t r;
    asm("v_cvt_pk_bf16_f32 %0, %1, %2" : "=v"(r) : "v"(lo), "v"(hi));
    return r;
}

__device__ __forceinline__ void gll16(const void* g, void* l) {
    __builtin_amdgcn_global_load_lds((const __attribute__((address_space(1))) unsigned int*)g,
                                     (__attribute__((address_space(3))) unsigned int*)l,
                                     16, 0, 0);
}

// XCD-aware bijective remap of the linear workgroup id (nwg % 8 == 0 everywhere)
__device__ __forceinline__ int xcd_lin() {
    int gx = gridDim.x;
    int n  = gx * gridDim.y;
    int lin = blockIdx.y * gx + blockIdx.x;
    int cpx = n >> 3;
    return (lin & 7) * cpx + (lin >> 3);
}

// ---------------------------------------------------------------------------
// Kernel 1: fp32 -> bf16 conversion + weight/bias concat
// ---------------------------------------------------------------------------
__global__ __launch_bounds__(256) void convert_kernel(
    const float* __restrict__ x,
    const float* __restrict__ Wq, const float* __restrict__ Wk,
    const float* __restrict__ Wv, const float* __restrict__ Wo,
    const float* __restrict__ bq, const float* __restrict__ bk, const float* __restrict__ bv,
    ushort_t* __restrict__ xb, ushort_t* __restrict__ wqkv,
    ushort_t* __restrict__ wob, float* __restrict__ bqkv)
{
    int idx = blockIdx.x * 256 + threadIdx.x;
    const float* src; ushort_t* dst; int off;
    if (idx < 1048576) { src = x; dst = xb; off = idx * 4; }
    else if (idx < 1835008) {
        int e = (idx - 1048576) * 4;
        int wi = e >> 20; off = e & 1048575;
        src = (wi == 0) ? Wq : ((wi == 1) ? Wk : Wv);
        dst = wqkv + ((size_t)wi << 20);
    } else { off = (idx - 1835008) * 4; src = Wo; dst = wob; }
    float4 v = *reinterpret_cast<const float4*>(src + off);
    ushort_t o0 = f2bf(v.x), o1 = f2bf(v.y), o2 = f2bf(v.z), o3 = f2bf(v.w);
    ushort_t* d = dst + off;
    d[0] = o0; d[1] = o1; d[2] = o2; d[3] = o3;
    if (idx < 768) {
        int wi = idx >> 8; int o4 = (idx & 255) * 4;
        const float* bsrc = (wi == 0) ? bq : ((wi == 1) ? bk : bv);
        *reinterpret_cast<float4*>(bqkv + wi * 1024 + o4) =
            *reinterpret_cast<const float4*>(bsrc + o4);
    }
}

// ---------------------------------------------------------------------------
// Kernel 2: GEMM C[M,N] = A[M,K] * B[N,K]^T + bias, dbuf staging,
// counted-vmcnt two-barrier pipeline (T4), XCD swizzle.
// WRITE_VT: for n-cols >= 2048 (the V third), write ONLY the transposed copy
// Vt[bh][d][s] (attn never reads V from qkv).
// ---------------------------------------------------------------------------
template<int WRITE_BF16, int BN, int WRITE_VT>
__global__ __launch_bounds__(256) void gemm_nt(
    const ushort_t* __restrict__ A, const ushort_t* __restrict__ Bm,
    const float* __restrict__ bias, void* __restrict__ Cout,
    ushort_t* __restrict__ Vt,
    int M, int N, int K)
{
    constexpr int NT = BN / 32;          // n-frags per wave
    __shared__ ushort_t As[2][128 * 32];
    __shared__ ushort_t Bs[2][BN * 32];

    const int tid  = threadIdx.x;
    const int lane = tid & 63;
    const int wv   = tid >> 6;

    const int sw = xcd_lin();
    const int bx = sw % gridDim.x;
    const int by = sw / gridDim.x;
    const int m0 = by * 128;
    const int n0 = bx * BN;

    const int wr   = wv >> 1, wc = wv & 1;
    const int g    = lane >> 4, c = lane & 15;

    f32x4 acc[4][NT] = {};

    const int srow = lane >> 2;
    const int scol = (lane & 3) * 8;
    const ushort_t* Ag = A  + (size_t)(m0 + wv * 32 + srow) * K + scol;
    const ushort_t* Bg = Bm + (size_t)(n0 + (BN == 128 ? wv * 32 : wv * 16) + srow) * K + scol;

    auto STAGE = [&](int b, int k0) {
        gll16(Ag + k0,          &As[b][(wv * 32) * 32]);
        gll16(Ag + 16 * K + k0, &As[b][(wv * 32 + 16) * 32]);
        if (BN == 128) {
            gll16(Bg + k0,          &Bs[b][(wv * 32) * 32]);
            gll16(Bg + 16 * K + k0, &Bs[b][(wv * 32 + 16) * 32]);
        } else {
            gll16(Bg + k0,          &Bs[b][(wv * 16) * 32]);
        }
    };

    STAGE(0, 0);
    int cur = 0;
    for (int k0 = 0; k0 < K; k0 += 32) {
        if (k0 + 32 < K) {
            STAGE(cur ^ 1, k0 + 32);
            if (BN == 128) asm volatile("s_waitcnt vmcnt(4)" ::: "memory");
            else           asm volatile("s_waitcnt vmcnt(3)" ::: "memory");
        } else {
            asm volatile("s_waitcnt vmcnt(0)" ::: "memory");
        }
        __builtin_amdgcn_sched_barrier(0);
        __builtin_amdgcn_s_barrier();          // A: this tile's loads landed everywhere
        __builtin_amdgcn_sched_barrier(0);

        short8 af[4], bf[NT];
        #pragma unroll
        for (int i = 0; i < 4; i++)
            af[i] = *reinterpret_cast<const short8*>(&As[cur][(wr * 64 + i * 16 + c) * 32 + g * 8]);
        #pragma unroll
        for (int j = 0; j < NT; j++)
            bf[j] = *reinterpret_cast<const short8*>(&Bs[cur][(wc * (BN / 2) + j * 16 + c) * 32 + g * 8]);
        #pragma unroll
        for (int i = 0; i < 4; i++)
            #pragma unroll
            for (int j = 0; j < NT; j++)
                acc[i][j] = __builtin_amdgcn_mfma_f32_16x16x32_bf16(af[i], bf[j], acc[i][j], 0, 0, 0);

        asm volatile("s_waitcnt lgkmcnt(0)" ::: "memory");
        __builtin_amdgcn_sched_barrier(0);
        __builtin_amdgcn_s_barrier();          // B: everyone done reading buf[cur]
        __builtin_amdgcn_sched_barrier(0);
        cur ^= 1;
    }

    #pragma unroll
    for (int i = 0; i < 4; i++) {
        int row = m0 + wr * 64 + i * 16 + 4 * g;
        #pragma unroll
        for (int j = 0; j < NT; j++) {
            int col = n0 + wc * (BN / 2) + j * 16 + c;
            float bv_ = bias[col];
            float v0 = acc[i][j][0] + bv_;
            float v1 = acc[i][j][1] + bv_;
            float v2 = acc[i][j][2] + bv_;
            float v3 = acc[i][j][3] + bv_;
            if (WRITE_VT && col >= 2048) {
                int dcol = col - 2048;
                int hv = dcol >> 6, dd = dcol & 63;
                int bb = row >> 11, ss = row & 2047;
                uint_t w0 = cvtpk(v0, v1);
                uint_t w1 = cvtpk(v2, v3);
                uint_t* vp = reinterpret_cast<uint_t*>(
                    Vt + (((size_t)(bb * 16 + hv) * 64 + dd) * 2048 + ss));
                vp[0] = w0; vp[1] = w1;
            } else if (WRITE_BF16) {
                ushort_t* cp = (ushort_t*)Cout;
                cp[(size_t)(row + 0) * N + col] = f2bf(v0);
                cp[(size_t)(row + 1) * N + col] = f2bf(v1);
                cp[(size_t)(row + 2) * N + col] = f2bf(v2);
                cp[(size_t)(row + 3) * N + col] = f2bf(v3);
            } else {
                float* cp = (float*)Cout;
                cp[(size_t)(row + 0) * N + col] = v0;
                cp[(size_t)(row + 1) * N + col] = v1;
                cp[(size_t)(row + 2) * N + col] = v2;
                cp[(size_t)(row + 3) * N + col] = v3;
            }
        }
    }
}

// ---------------------------------------------------------------------------
// Kernel 3: flash attention, 4-way intra-block KV-split for 8 waves/SIMD.
// 1024 thr = 16 warps = 4 q-warps (wq, 32 q-rows each) x 4 KV-quarters (kq,
// 512 kk each). KVBLK=32, per-quarter dbuf 16KB (64KB total) -> 2 blocks/CU
// -> 32 waves/CU = 8 waves/SIMD (needs VGPR<=64, enforced by launch_bounds).
// Two-barrier counted-vmcnt loop (R12-verified). K rows staged sigma-swapped
// (bit2<->bit3 per 16-group) -> P pack lane-local. No-max softmax, raw exp2.
// Combine = 2-pass LDS add tree across quarters.
// ---------------------------------------------------------------------------
__global__ __launch_bounds__(1024, 8) void attn_kernel(
    const ushort_t* __restrict__ qkv, const ushort_t* __restrict__ Vt,
    ushort_t* __restrict__ out)
{
    // bytes: quarter kq at kq*16384; buffer bb at +bb*8192; K 4KB + V 4KB
    __shared__ ushort_t smem[32768];   // 64 KB

    const int tid  = threadIdx.x;
    const int lane = tid & 63;
    const int wv   = tid >> 6;        // 0..15
    const int wq   = wv & 3;          // q-warp
    const int kq   = wv >> 2;         // KV quarter
    const int sw   = xcd_lin();
    const int qt   = sw & 15;
    const int bh   = sw >> 4;
    const int b = bh >> 4, h = bh & 15;
    const int c  = lane & 31;
    const int hh = lane >> 5;

    const int q0 = qt * 128 + wq * 32;
    const size_t tokbase = (size_t)b * 2048;

    // Q fragments (B operand), pre-scaled by LOG2E/8 (log2-domain scores)
    short8 qf[4];
    {
        const ushort_t* qg = qkv + (tokbase + q0 + c) * 3072 + h * 64 + hh * 8;
        #pragma unroll
        for (int s = 0; s < 4; s++) {
            short8 v = *reinterpret_cast<const short8*>(qg + s * 16);
            short8 o;
            #pragma unroll
            for (int e = 0; e < 8; e++)
                o[e] = (short)f2bf(bf2f((ushort_t)v[e]) * (0.125f * LOG2E));
            qf[s] = o;
        }
    }

    // staging sources. K: sigma = swap bits2<->3 of kk within 16-groups.
    // warp stages LDS rho-rows wq*8 + l3; orig kk = swap23(rho):
    const int l8 = lane & 7;
    const int l3 = lane >> 3;         // 0..7
    const int kkA = (l3 & 3) + 4 * (wq & 1) + 8 * ((l3 >> 2) & 1) + 16 * (wq >> 1);
    const ushort_t* kg0 = qkv + (tokbase + kq * 512 + kkA) * 3072
                              + 1024 + h * 64 + ((l8 ^ l3) * 8);
    // V tile [d 0..63][kk 0..31]: row = wq*16 + (l>>2); stored chunk l&3;
    // swizzle key (row>>1)&3 = (l>>3)&3 (wq*8 = 0 mod 4)
    const int vrow = wq * 16 + ((lane >> 2) & 15);
    const int vch  = (lane & 3) ^ ((lane >> 3) & 3);
    const ushort_t* vg0 = Vt + ((size_t)bh * 64 + vrow) * 2048 + kq * 512 + vch * 8;

    f32x16 oacc[2] = {};
    f32x16 sc0;
    float p0 = 0.f, p1 = 0.f, p2 = 0.f, p3 = 0.f;

    auto STAGE = [&](int bb, int kt) {
        char* Kd = (char*)smem + kq * 16384 + bb * 8192 + wq * 1024;
        char* Vd = Kd + 4096;
        gll16(kg0 + (size_t)(kt * 32) * 3072, Kd);
        gll16(vg0 + kt * 32,                  Vd);
    };

    STAGE(0, 0);
    int cur = 0;

    for (int it = 0; it < 16; it++) {
        if (it + 1 < 16) {
            STAGE(cur ^ 1, it + 1);                       // 2 newest = next tile
            asm volatile("s_waitcnt vmcnt(2)" ::: "memory");
        } else {
            asm volatile("s_waitcnt vmcnt(0)" ::: "memory");
        }
        __builtin_amdgcn_sched_barrier(0);
        __builtin_amdgcn_s_barrier();          // A: tile-it loads landed block-wide
        __builtin_amdgcn_sched_barrier(0);

        const char* KlB = (const char*)smem + kq * 16384 + cur * 8192;
        const char* VlB = KlB + 4096;

        // S^T[rho][q]: 32 kk rows x 32 q, K=64 over 4 st-slices
        sc0 = f32x16{};
        __builtin_amdgcn_s_setprio(1);
        #pragma unroll
        for (int st = 0; st < 4; st++) {
            const int chB = (((2 * st + hh) ^ (c & 7)) << 4);
            short8 ak = *reinterpret_cast<const short8*>(KlB + c * 128 + chB);
            sc0 = __builtin_amdgcn_mfma_f32_32x32x16_bf16(ak, qf[st], sc0, 0, 0, 0);
        }
        __builtin_amdgcn_s_setprio(0);

        // P = 2^S; 4-way ILP partial sums for l
        #pragma unroll
        for (int r = 0; r < 16; r += 4) {
            sc0[r]   = EXP2(sc0[r]);   p0 += sc0[r];
            sc0[r+1] = EXP2(sc0[r+1]); p1 += sc0[r+1];
            sc0[r+2] = EXP2(sc0[r+2]); p2 += sc0[r+2];
            sc0[r+3] = EXP2(sc0[r+3]); p3 += sc0[r+3];
        }

        // ks-steps s=0,1: LANE-LOCAL pack (sigma makes slots == B-frag order)
        __builtin_amdgcn_s_setprio(1);
        #pragma unroll
        for (int s = 0; s < 2; s++) {
            const int rb = s * 8;
            union { uint_t u[4]; short8 s8; } pu;
            pu.u[0] = cvtpk(sc0[rb + 0], sc0[rb + 1]);
            pu.u[1] = cvtpk(sc0[rb + 2], sc0[rb + 3]);
            pu.u[2] = cvtpk(sc0[rb + 4], sc0[rb + 5]);
            pu.u[3] = cvtpk(sc0[rb + 6], sc0[rb + 7]);

            const int chV = (((2 * s + hh) ^ ((c >> 1) & 3)) << 4);
            short8 av0 = *reinterpret_cast<const short8*>(VlB + (c     ) * 64 + chV);
            short8 av1 = *reinterpret_cast<const short8*>(VlB + (32 + c) * 64 + chV);
            oacc[0] = __builtin_amdgcn_mfma_f32_32x32x16_bf16(av0, pu.s8, oacc[0], 0, 0, 0);
            oacc[1] = __builtin_amdgcn_mfma_f32_32x32x16_bf16(av1, pu.s8, oacc[1], 0, 0, 0);
        }
        __builtin_amdgcn_s_setprio(0);

        asm volatile("s_waitcnt lgkmcnt(0)" ::: "memory");
        __builtin_amdgcn_sched_barrier(0);
        __builtin_amdgcn_s_barrier();          // B: everyone done reading buf[cur]
        __builtin_amdgcn_sched_barrier(0);
        cur ^= 1;
    }

    // ---- combine across quarters (kq 1..3 dump; kq 0 adds). Two passes. ----
    float l_own = (p0 + p1) + (p2 + p3);
    float* dump = (float*)smem;
    __syncthreads();   // all PV reads drained before smem reuse
    if (kq) {
        int di = (((kq - 1) * 4 + wq) * 64 + lane) * 17;
        #pragma unroll
        for (int r = 0; r < 16; r++) dump[di + r] = oacc[0][r];
        dump[di + 16] = l_own;
    }
    __syncthreads();
    if (!kq) {
        #pragma unroll
        for (int src = 0; src < 3; src++) {
            int di = ((src * 4 + wq) * 64 + lane) * 17;
            #pragma unroll
            for (int r = 0; r < 16; r++) oacc[0][r] += dump[di + r];
            l_own += dump[di + 16];
        }
    }
    __syncthreads();
    if (kq) {
        int di = (((kq - 1) * 4 + wq) * 64 + lane) * 17;
        #pragma unroll
        for (int r = 0; r < 16; r++) dump[di + r] = oacc[1][r];
    }
    __syncthreads();
    if (!kq) {
        #pragma unroll
        for (int src = 0; src < 3; src++) {
            int di = ((src * 4 + wq) * 64 + lane) * 17;
            #pragma unroll
            for (int r = 0; r < 16; r++) oacc[1][r] += dump[di + r];
        }
    }
    __syncthreads();   // dump reads done; Olw region may overwrite

    if (!kq) {
        float l_tot = l_own + __shfl_xor(l_own, 32);
        float invl = 1.0f / l_tot;

        ushort_t* Olw = (ushort_t*)((char*)smem + wq * 4608);
        #pragma unroll
        for (int td = 0; td < 2; td++)
            #pragma unroll
            for (int rr = 0; rr < 4; rr++)
                #pragma unroll
                for (int j2 = 0; j2 < 2; j2++) {
                    int r = 4 * rr + 2 * j2;
                    float v0 = (td == 0) ? oacc[0][r] : oacc[1][r];
                    float v1 = (td == 0) ? oacc[0][r + 1] : oacc[1][r + 1];
                    uint_t wd = cvtpk(v0 * invl, v1 * invl);
                    int dcol = 32 * td + 4 * hh + 8 * rr + 2 * j2;
                    *reinterpret_cast<uint_t*>(&Olw[c * 72 + dcol]) = wd;
                }
        // within-warp cross-lane LDS: compiler lgkmcnt orders write->read
        int row = lane >> 1;
        int e0  = (lane & 1) * 32;
        ushort_t* og = out + (tokbase + q0 + row) * 1024 + h * 64 + e0;
        #pragma unroll
        for (int k2 = 0; k2 < 4; k2++) {
            short8 v;
            #pragma unroll
            for (int e = 0; e < 8; e++) v[e] = (short)Olw[row * 72 + e0 + k2 * 8 + e];
            *reinterpret_cast<short8*>(og + k2 * 8) = v;
        }
    }
}

// ---------------------------------------------------------------------------
extern "C" void kernel_launch(void* const* d_in, const int* in_sizes, int n_in,
                              void* d_out, int out_size, void* d_ws, size_t ws_size,
                              hipStream_t stream) {
    const float* x  = (const float*)d_in[0];
    const float* Wq = (const float*)d_in[1];
    const float* bq = (const float*)d_in[2];
    const float* Wk = (const float*)d_in[3];
    const float* bk = (const float*)d_in[4];
    const float* Wv = (const float*)d_in[5];
    const float* bv = (const float*)d_in[6];
    const float* Wo = (const float*)d_in[7];
    const float* bo = (const float*)d_in[8];

    uintptr_t w = (uintptr_t)d_ws;
    ushort_t* xb    = (ushort_t*)w;  w += 8388608;    // 4096x1024 bf16
    ushort_t* wqkv  = (ushort_t*)w;  w += 6291456;    // 3072x1024 bf16
    ushort_t* wob   = (ushort_t*)w;  w += 2097152;    // 1024x1024 bf16
    float*    bqkv  = (float*)w;     w += 12288;      // 3072 fp32
    ushort_t* qkv   = (ushort_t*)w;  w += 25165824;   // 4096x3072 bf16 (V cols unused)
    ushort_t* attno = (ushort_t*)w;  w += 8388608;    // 4096x1024 bf16
    ushort_t* Vt    = (ushort_t*)w;  w += 8388608;    // 32bh x 64d x 2048s bf16

    convert_kernel<<<8192, 256, 0, stream>>>(x, Wq, Wk, Wv, Wo, bq, bk, bv,
                                             xb, wqkv, wob, bqkv);
    gemm_nt<1, 128, 1><<<dim3(24, 32), 256, 0, stream>>>(xb, wqkv, bqkv, qkv, Vt, 4096, 3072, 1024);
    attn_kernel<<<dim3(16, 32), 1024, 0, stream>>>(qkv, Vt, attno);
    gemm_nt<0, 64, 0><<<dim3(16, 32), 256, 0, stream>>>(attno, wob, bo, (void*)d_out, nullptr, 4096, 1024, 1024);
}

// Round 15
// 107.407 us; speedup vs baseline: 3.5815x; 3.5815x over previous
//
#include <hip/hip_runtime.h>
#include <hip/hip_bf16.h>

typedef __attribute__((ext_vector_type(8))) short short8;
typedef __attribute__((ext_vector_type(4))) float f32x4;
typedef __attribute__((ext_vector_type(16))) float f32x16;
typedef unsigned short ushort_t;
typedef unsigned int uint_t;

#define LOG2E 1.4426950408889634f

#if __has_builtin(__builtin_amdgcn_exp2f)
#define EXP2(x) __builtin_amdgcn_exp2f(x)
#else
#define EXP2(x) exp2f(x)
#endif

__device__ __forceinline__ ushort_t f2bf(float f) {
    union { float f; unsigned int i; } x; x.f = f;
    unsigned int r = x.i + 0x7FFF + ((x.i >> 16) & 1);   // RNE
    return (ushort_t)(r >> 16);
}
__device__ __forceinline__ float bf2f(ushort_t u) {
    union { unsigned int i; float f; } x; x.i = ((unsigned int)u) << 16; return x.f;
}
__device__ __forceinline__ uint_t cvtpk(float lo, float hi) {
    uint_t r;
    asm("v_cvt_pk_bf16_f32 %0, %1, %2" : "=v"(r) : "v"(lo), "v"(hi));
    return r;
}

__device__ __forceinline__ void gll16(const void* g, void* l) {
    __builtin_amdgcn_global_load_lds((const __attribute__((address_space(1))) unsigned int*)g,
                                     (__attribute__((address_space(3))) unsigned int*)l,
                                     16, 0, 0);
}

// XCD-aware bijective remap of the linear workgroup id (nwg % 8 == 0 everywhere)
__device__ __forceinline__ int xcd_lin() {
    int gx = gridDim.x;
    int n  = gx * gridDim.y;
    int lin = blockIdx.y * gx + blockIdx.x;
    int cpx = n >> 3;
    return (lin & 7) * cpx + (lin >> 3);
}

// ---------------------------------------------------------------------------
// Kernel 1: fp32 -> bf16 conversion + weight/bias concat
// ---------------------------------------------------------------------------
__global__ __launch_bounds__(256) void convert_kernel(
    const float* __restrict__ x,
    const float* __restrict__ Wq, const float* __restrict__ Wk,
    const float* __restrict__ Wv, const float* __restrict__ Wo,
    const float* __restrict__ bq, const float* __restrict__ bk, const float* __restrict__ bv,
    ushort_t* __restrict__ xb, ushort_t* __restrict__ wqkv,
    ushort_t* __restrict__ wob, float* __restrict__ bqkv)
{
    int idx = blockIdx.x * 256 + threadIdx.x;
    const float* src; ushort_t* dst; int off;
    if (idx < 1048576) { src = x; dst = xb; off = idx * 4; }
    else if (idx < 1835008) {
        int e = (idx - 1048576) * 4;
        int wi = e >> 20; off = e & 1048575;
        src = (wi == 0) ? Wq : ((wi == 1) ? Wk : Wv);
        dst = wqkv + ((size_t)wi << 20);
    } else { off = (idx - 1835008) * 4; src = Wo; dst = wob; }
    float4 v = *reinterpret_cast<const float4*>(src + off);
    ushort_t o0 = f2bf(v.x), o1 = f2bf(v.y), o2 = f2bf(v.z), o3 = f2bf(v.w);
    ushort_t* d = dst + off;
    d[0] = o0; d[1] = o1; d[2] = o2; d[3] = o3;
    if (idx < 768) {
        int wi = idx >> 8; int o4 = (idx & 255) * 4;
        const float* bsrc = (wi == 0) ? bq : ((wi == 1) ? bk : bv);
        *reinterpret_cast<float4*>(bqkv + wi * 1024 + o4) =
            *reinterpret_cast<const float4*>(bsrc + o4);
    }
}

// ---------------------------------------------------------------------------
// Kernel 2: GEMM C[M,N] = A[M,K] * B[N,K]^T + bias, dbuf staging,
// counted-vmcnt two-barrier pipeline (T4), XCD swizzle.
// WRITE_VT: for n-cols >= 2048 (the V third), write ONLY the transposed copy
// Vt[bh][d][s] (attn never reads V from qkv).
// ---------------------------------------------------------------------------
template<int WRITE_BF16, int BN, int WRITE_VT>
__global__ __launch_bounds__(256) void gemm_nt(
    const ushort_t* __restrict__ A, const ushort_t* __restrict__ Bm,
    const float* __restrict__ bias, void* __restrict__ Cout,
    ushort_t* __restrict__ Vt,
    int M, int N, int K)
{
    constexpr int NT = BN / 32;          // n-frags per wave
    __shared__ ushort_t As[2][128 * 32];
    __shared__ ushort_t Bs[2][BN * 32];

    const int tid  = threadIdx.x;
    const int lane = tid & 63;
    const int wv   = tid >> 6;

    const int sw = xcd_lin();
    const int bx = sw % gridDim.x;
    const int by = sw / gridDim.x;
    const int m0 = by * 128;
    const int n0 = bx * BN;

    const int wr   = wv >> 1, wc = wv & 1;
    const int g    = lane >> 4, c = lane & 15;

    f32x4 acc[4][NT] = {};

    const int srow = lane >> 2;
    const int scol = (lane & 3) * 8;
    const ushort_t* Ag = A  + (size_t)(m0 + wv * 32 + srow) * K + scol;
    const ushort_t* Bg = Bm + (size_t)(n0 + (BN == 128 ? wv * 32 : wv * 16) + srow) * K + scol;

    auto STAGE = [&](int b, int k0) {
        gll16(Ag + k0,          &As[b][(wv * 32) * 32]);
        gll16(Ag + 16 * K + k0, &As[b][(wv * 32 + 16) * 32]);
        if (BN == 128) {
            gll16(Bg + k0,          &Bs[b][(wv * 32) * 32]);
            gll16(Bg + 16 * K + k0, &Bs[b][(wv * 32 + 16) * 32]);
        } else {
            gll16(Bg + k0,          &Bs[b][(wv * 16) * 32]);
        }
    };

    STAGE(0, 0);
    int cur = 0;
    for (int k0 = 0; k0 < K; k0 += 32) {
        if (k0 + 32 < K) {
            STAGE(cur ^ 1, k0 + 32);
            if (BN == 128) asm volatile("s_waitcnt vmcnt(4)" ::: "memory");
            else           asm volatile("s_waitcnt vmcnt(3)" ::: "memory");
        } else {
            asm volatile("s_waitcnt vmcnt(0)" ::: "memory");
        }
        __builtin_amdgcn_sched_barrier(0);
        __builtin_amdgcn_s_barrier();          // A: this tile's loads landed everywhere
        __builtin_amdgcn_sched_barrier(0);

        short8 af[4], bf[NT];
        #pragma unroll
        for (int i = 0; i < 4; i++)
            af[i] = *reinterpret_cast<const short8*>(&As[cur][(wr * 64 + i * 16 + c) * 32 + g * 8]);
        #pragma unroll
        for (int j = 0; j < NT; j++)
            bf[j] = *reinterpret_cast<const short8*>(&Bs[cur][(wc * (BN / 2) + j * 16 + c) * 32 + g * 8]);
        #pragma unroll
        for (int i = 0; i < 4; i++)
            #pragma unroll
            for (int j = 0; j < NT; j++)
                acc[i][j] = __builtin_amdgcn_mfma_f32_16x16x32_bf16(af[i], bf[j], acc[i][j], 0, 0, 0);

        asm volatile("s_waitcnt lgkmcnt(0)" ::: "memory");
        __builtin_amdgcn_sched_barrier(0);
        __builtin_amdgcn_s_barrier();          // B: everyone done reading buf[cur]
        __builtin_amdgcn_sched_barrier(0);
        cur ^= 1;
    }

    #pragma unroll
    for (int i = 0; i < 4; i++) {
        int row = m0 + wr * 64 + i * 16 + 4 * g;
        #pragma unroll
        for (int j = 0; j < NT; j++) {
            int col = n0 + wc * (BN / 2) + j * 16 + c;
            float bv_ = bias[col];
            float v0 = acc[i][j][0] + bv_;
            float v1 = acc[i][j][1] + bv_;
            float v2 = acc[i][j][2] + bv_;
            float v3 = acc[i][j][3] + bv_;
            if (WRITE_VT && col >= 2048) {
                // V column: write transposed only. rows row..row+3 -> s..s+3 contiguous
                int dcol = col - 2048;
                int hv = dcol >> 6, dd = dcol & 63;
                int bb = row >> 11, ss = row & 2047;
                uint_t w0 = cvtpk(v0, v1);
                uint_t w1 = cvtpk(v2, v3);
                uint_t* vp = reinterpret_cast<uint_t*>(
                    Vt + (((size_t)(bb * 16 + hv) * 64 + dd) * 2048 + ss));
                vp[0] = w0; vp[1] = w1;
            } else if (WRITE_BF16) {
                ushort_t* cp = (ushort_t*)Cout;
                cp[(size_t)(row + 0) * N + col] = f2bf(v0);
                cp[(size_t)(row + 1) * N + col] = f2bf(v1);
                cp[(size_t)(row + 2) * N + col] = f2bf(v2);
                cp[(size_t)(row + 3) * N + col] = f2bf(v3);
            } else {
                float* cp = (float*)Cout;
                cp[(size_t)(row + 0) * N + col] = v0;
                cp[(size_t)(row + 1) * N + col] = v1;
                cp[(size_t)(row + 2) * N + col] = v2;
                cp[(size_t)(row + 3) * N + col] = v3;
            }
        }
    }
}

// ---------------------------------------------------------------------------
// Kernel 3: flash attention, intra-block KV-split, counted-vmcnt two-barrier
// pipeline. 512 thr = 8 warps: warps 0-3 KV [0,1024), 4-7 [1024,2048),
// same 128 q-rows. KVBLK=64, per-half dbuf 32KB (64KB) -> 4 waves/SIMD.
// K rows staged bit2<->bit3 swapped (per 16-row group) so QK^T C/D slots are
// exactly PV's B-operand k-slots -> P pack is LANE-LOCAL (no shfl, no selects).
// No-max softmax (log2 domain), raw v_exp_f32; combine = LDS add.
// ---------------------------------------------------------------------------
__global__ __launch_bounds__(512, 4) void attn_kernel(
    const ushort_t* __restrict__ qkv, const ushort_t* __restrict__ Vt,
    ushort_t* __restrict__ out)
{
    // ushort layout: half g2 at g2*16384; buffer bb at +bb*8192; K 4096 + V 4096
    __shared__ ushort_t smem[32768];

    const int tid  = threadIdx.x;
    const int lane = tid & 63;
    const int wv   = tid >> 6;        // 0..7
    const int wvi  = wv & 3;
    const int g2   = wv >> 2;         // KV half
    const int sw   = xcd_lin();
    const int qt   = sw & 15;
    const int bh   = sw >> 4;
    const int b = bh >> 4, h = bh & 15;
    const int c  = lane & 31;
    const int hh = lane >> 5;

    const int q0 = qt * 128 + wvi * 32;
    const size_t tokbase = (size_t)b * 2048;

    // Q fragments (B operand), pre-scaled by LOG2E/8 (log2-domain scores)
    short8 qf[4];
    {
        const ushort_t* qg = qkv + (tokbase + q0 + c) * 3072 + h * 64 + hh * 8;
        #pragma unroll
        for (int s = 0; s < 4; s++) {
            short8 v = *reinterpret_cast<const short8*>(qg + s * 16);
            short8 o;
            #pragma unroll
            for (int e = 0; e < 8; e++)
                o[e] = (short)f2bf(bf2f((ushort_t)v[e]) * (0.125f * LOG2E));
            qf[s] = o;
        }
    }

    // staging source pointers (XOR pre-swizzle in the global address).
    // K: sigma_K = swap bits 2<->3 within each 16-row group. Lane stages
    // LDS rho-rows {l3, l3+8}; fetches original rows {kkA, kkA+4}.
    // LDS XOR key stays l3 (= rho&7, invariant under the swap).
    const int l8 = lane & 7;
    const int l3 = lane >> 3;         // 0..7
    const int kkA = (l3 & 3) + 8 * ((l3 >> 2) & 1);
    const ushort_t* kg0 = qkv + (tokbase + g2 * 1024 + wvi * 16 + kkA) * 3072
                              + 1024 + h * 64 + (l8 ^ l3) * 8;
    const ushort_t* vg0 = Vt + ((size_t)bh * 64 + wvi * 16 + l3) * 2048
                             + g2 * 1024 + (l8 ^ l3) * 8;

    f32x16 oacc[2] = {};
    f32x16 sc[2];
    float l0 = 0.f, l1 = 0.f, l2 = 0.f, l3s = 0.f;

    auto STAGE = [&](int bb, int kt) {
        char* Kd = (char*)smem + g2 * 32768 + bb * 16384 + wvi * 2048;
        char* Vd = Kd + 8192;
        const ushort_t* ks = kg0 + (size_t)(kt * 64) * 3072;
        gll16(ks,                     Kd);
        gll16(ks + (size_t)4 * 3072,  Kd + 1024);   // rho-rows 8..15 hold kkA+4
        const ushort_t* vs = vg0 + kt * 64;
        gll16(vs,            Vd);
        gll16(vs + 8 * 2048, Vd + 1024);
    };

    STAGE(0, 0);
    int cur = 0;

    for (int it = 0; it < 16; it++) {
        if (it + 1 < 16) {
            STAGE(cur ^ 1, it + 1);                       // 4 newest loads = next tile
            asm volatile("s_waitcnt vmcnt(4)" ::: "memory");
        } else {
            asm volatile("s_waitcnt vmcnt(0)" ::: "memory");
        }
        __builtin_amdgcn_sched_barrier(0);
        __builtin_amdgcn_s_barrier();          // A: tile-it loads landed everywhere
        __builtin_amdgcn_sched_barrier(0);

        const char* KlB = (const char*)smem + g2 * 32768 + cur * 16384;
        const char* VlB = KlB + 8192;

        // S^T[rho][q] = Ksig · Q^T (log2 domain)
        sc[0] = f32x16{}; sc[1] = f32x16{};
        __builtin_amdgcn_s_setprio(1);
        #pragma unroll
        for (int st = 0; st < 4; st++) {
            const int chB = (((2 * st + hh) ^ (c & 7)) << 4);
            short8 ak0 = *reinterpret_cast<const short8*>(KlB + (c     ) * 128 + chB);
            short8 ak1 = *reinterpret_cast<const short8*>(KlB + (32 + c) * 128 + chB);
            sc[0] = __builtin_amdgcn_mfma_f32_32x32x16_bf16(ak0, qf[st], sc[0], 0, 0, 0);
            sc[1] = __builtin_amdgcn_mfma_f32_32x32x16_bf16(ak1, qf[st], sc[1], 0, 0, 0);
        }
        __builtin_amdgcn_s_setprio(0);

        // P = 2^S directly; 4-way ILP partial sums for l
        #pragma unroll
        for (int t = 0; t < 2; t++) {
            #pragma unroll
            for (int r = 0; r < 16; r += 4) {
                sc[t][r]   = EXP2(sc[t][r]);   l0  += sc[t][r];
                sc[t][r+1] = EXP2(sc[t][r+1]); l1  += sc[t][r+1];
                sc[t][r+2] = EXP2(sc[t][r+2]); l2  += sc[t][r+2];
                sc[t][r+3] = EXP2(sc[t][r+3]); l3s += sc[t][r+3];
            }
        }

        // per ks-step s (kk 16s..16s+15): LANE-LOCAL pack (4 cvt_pk), then PV
        __builtin_amdgcn_s_setprio(1);
        #pragma unroll
        for (int s = 0; s < 4; s++) {
            const int t0 = s >> 1;
            const int rb = (s & 1) * 8;
            union { uint_t u[4]; short8 s8; } pu;
            pu.u[0] = cvtpk(sc[t0][rb + 0], sc[t0][rb + 1]);
            pu.u[1] = cvtpk(sc[t0][rb + 2], sc[t0][rb + 3]);
            pu.u[2] = cvtpk(sc[t0][rb + 4], sc[t0][rb + 5]);
            pu.u[3] = cvtpk(sc[t0][rb + 6], sc[t0][rb + 7]);

            const int chB = (((2 * s + hh) ^ (c & 7)) << 4);
            short8 av0 = *reinterpret_cast<const short8*>(VlB + (c     ) * 128 + chB);
            short8 av1 = *reinterpret_cast<const short8*>(VlB + (32 + c) * 128 + chB);
            oacc[0] = __builtin_amdgcn_mfma_f32_32x32x16_bf16(av0, pu.s8, oacc[0], 0, 0, 0);
            oacc[1] = __builtin_amdgcn_mfma_f32_32x32x16_bf16(av1, pu.s8, oacc[1], 0, 0, 0);
        }
        __builtin_amdgcn_s_setprio(0);

        asm volatile("s_waitcnt lgkmcnt(0)" ::: "memory");
        __builtin_amdgcn_sched_barrier(0);
        __builtin_amdgcn_s_barrier();          // B: everyone done reading buf[cur]
        __builtin_amdgcn_sched_barrier(0);
        cur ^= 1;
    }

    // ---- intra-block combine: half-1 dumps unnormalized O + l; half-0 adds ----
    float l_own = (l0 + l1) + (l2 + l3s);
    float* dump = (float*)smem;
    const int di = (wvi * 64 + lane) * 34;
    if (g2) {
        #pragma unroll
        for (int r = 0; r < 16; r++) { dump[di + r] = oacc[0][r]; dump[di + 16 + r] = oacc[1][r]; }
        dump[di + 32] = l_own;
    }
    __syncthreads();
    if (!g2) {
        #pragma unroll
        for (int r = 0; r < 16; r++) { oacc[0][r] += dump[di + r]; oacc[1][r] += dump[di + 16 + r]; }
        l_own += dump[di + 32];
        float l_tot = l_own + __shfl_xor(l_own, 32);
        float invl = 1.0f / l_tot;

        // transpose via LDS (region disjoint from dump), coalesced bf16 store
        ushort_t* Olw = (ushort_t*)((char*)smem + 36864 + wvi * 4608);
        #pragma unroll
        for (int td = 0; td < 2; td++)
            #pragma unroll
            for (int rr = 0; rr < 4; rr++)
                #pragma unroll
                for (int j2 = 0; j2 < 2; j2++) {
                    int r = 4 * rr + 2 * j2;
                    float v0 = (td == 0) ? oacc[0][r] : oacc[1][r];
                    float v1 = (td == 0) ? oacc[0][r + 1] : oacc[1][r + 1];
                    uint_t wd = cvtpk(v0 * invl, v1 * invl);
                    int dcol = 32 * td + 4 * hh + 8 * rr + 2 * j2;
                    *reinterpret_cast<uint_t*>(&Olw[c * 72 + dcol]) = wd;
                }
        // within-warp cross-lane LDS: compiler-emitted lgkmcnt orders write->read
        int row = lane >> 1;
        int e0  = (lane & 1) * 32;
        ushort_t* og = out + (tokbase + q0 + row) * 1024 + h * 64 + e0;
        #pragma unroll
        for (int k2 = 0; k2 < 4; k2++) {
            short8 v;
            #pragma unroll
            for (int e = 0; e < 8; e++) v[e] = (short)Olw[row * 72 + e0 + k2 * 8 + e];
            *reinterpret_cast<short8*>(og + k2 * 8) = v;
        }
    }
}

// ---------------------------------------------------------------------------
extern "C" void kernel_launch(void* const* d_in, const int* in_sizes, int n_in,
                              void* d_out, int out_size, void* d_ws, size_t ws_size,
                              hipStream_t stream) {
    const float* x  = (const float*)d_in[0];
    const float* Wq = (const float*)d_in[1];
    const float* bq = (const float*)d_in[2];
    const float* Wk = (const float*)d_in[3];
    const float* bk = (const float*)d_in[4];
    const float* Wv = (const float*)d_in[5];
    const float* bv = (const float*)d_in[6];
    const float* Wo = (const float*)d_in[7];
    const float* bo = (const float*)d_in[8];

    uintptr_t w = (uintptr_t)d_ws;
    ushort_t* xb    = (ushort_t*)w;  w += 8388608;    // 4096x1024 bf16
    ushort_t* wqkv  = (ushort_t*)w;  w += 6291456;    // 3072x1024 bf16
    ushort_t* wob   = (ushort_t*)w;  w += 2097152;    // 1024x1024 bf16
    float*    bqkv  = (float*)w;     w += 12288;      // 3072 fp32
    ushort_t* qkv   = (ushort_t*)w;  w += 25165824;   // 4096x3072 bf16 (V cols unused)
    ushort_t* attno = (ushort_t*)w;  w += 8388608;    // 4096x1024 bf16
    ushort_t* Vt    = (ushort_t*)w;  w += 8388608;    // 32bh x 64d x 2048s bf16

    convert_kernel<<<8192, 256, 0, stream>>>(x, Wq, Wk, Wv, Wo, bq, bk, bv,
                                             xb, wqkv, wob, bqkv);
    gemm_nt<1, 128, 1><<<dim3(24, 32), 256, 0, stream>>>(xb, wqkv, bqkv, qkv, Vt, 4096, 3072, 1024);
    attn_kernel<<<dim3(16, 32), 512, 0, stream>>>(qkv, Vt, attno);
    gemm_nt<0, 64, 0><<<dim3(16, 32), 256, 0, stream>>>(attno, wob, bo, (void*)d_out, nullptr, 4096, 1024, 1024);
}